// Round 1
// baseline (7178.574 us; speedup 1.0000x reference)
//
#include <hip/hip_runtime.h>
#include <hip/hip_bf16.h>

// Problem constants (from reference)
#define NNODES_MAX 50000
#define HID 128
#define NGRAPH 512

// ---------------------------------------------------------------------------
// Setup kernels: degree count, rsqrt, scan (CSR row_start), CSR fill
// ---------------------------------------------------------------------------

__global__ void k_count(const int* __restrict__ ei, int* __restrict__ deg, int E) {
    int e = blockIdx.x * blockDim.x + threadIdx.x;
    if (e < E) atomicAdd(&deg[ei[E + e]], 1);  // dst row
}

__global__ void k_dinv(const int* __restrict__ deg, float* __restrict__ dinv, int n) {
    int i = blockIdx.x * blockDim.x + threadIdx.x;
    if (i < n) dinv[i] = rsqrtf((float)deg[i] + 1.0f);  // +1 self-loop
}

// Single-block scan, 8 values/thread: exclusive prefix of deg -> row_start, cursor
__global__ void k_scan(const int* __restrict__ deg, int* __restrict__ row_start,
                       int* __restrict__ cursor, int n) {
    __shared__ int sm[1024];
    __shared__ int running_s;
    int tid = threadIdx.x;
    if (tid == 0) running_s = 0;
    __syncthreads();
    const int VPT = 8;
    for (int base = 0; base < n; base += 1024 * VPT) {
        int i0 = base + tid * VPT;
        int v[VPT];
        int lsum = 0;
#pragma unroll
        for (int j = 0; j < VPT; ++j) {
            int i = i0 + j;
            v[j] = (i < n) ? deg[i] : 0;
            lsum += v[j];
        }
        sm[tid] = lsum;
        __syncthreads();
#pragma unroll
        for (int off = 1; off < 1024; off <<= 1) {
            int t = (tid >= off) ? sm[tid - off] : 0;
            __syncthreads();
            sm[tid] += t;
            __syncthreads();
        }
        int r = running_s + sm[tid] - lsum;  // exclusive prefix for this thread's chunk
        int total = sm[1023];
#pragma unroll
        for (int j = 0; j < VPT; ++j) {
            int i = i0 + j;
            if (i < n) { row_start[i] = r; cursor[i] = r; }
            r += v[j];
        }
        __syncthreads();
        if (tid == 0) running_s += total;
        __syncthreads();
    }
    if (tid == 0) row_start[n] = running_s;
}

__global__ void k_fill(const int* __restrict__ ei, int* __restrict__ cursor,
                       int* __restrict__ src_sorted, int E) {
    int e = blockIdx.x * blockDim.x + threadIdx.x;
    if (e < E) {
        int s = ei[e];
        int d = ei[E + e];
        int pos = atomicAdd(&cursor[d], 1);
        src_sorted[pos] = s;
    }
}

// ---------------------------------------------------------------------------
// GEMMs
// ---------------------------------------------------------------------------

// Layer-1: x[N,3] @ W[3,128] -> H[N,128]   (thread per output element)
__global__ void k_gemm3(const float* __restrict__ X, const float* __restrict__ W,
                        float* __restrict__ Hout, int n) {
    int idx = blockIdx.x * blockDim.x + threadIdx.x;
    if (idx >= n * HID) return;
    int i = idx >> 7, c = idx & 127;
    float x0 = X[i * 3 + 0], x1 = X[i * 3 + 1], x2 = X[i * 3 + 2];
    Hout[idx] = x0 * W[c] + x1 * W[HID + c] + x2 * W[2 * HID + c];
}

// [N,128] @ [128,128] -> [N,128].  512 threads: c = tid&127, rg = tid>>7;
// thread computes 8 rows x 1 col.  W staged in LDS (64 KB -> 2 blocks/CU).
__global__ __launch_bounds__(512, 2) void k_gemm128(const float* __restrict__ X,
                                                    const float* __restrict__ W,
                                                    float* __restrict__ Hout, int n) {
    __shared__ float Ws[HID * HID];
    {
        const float4* W4 = (const float4*)W;
        float4* Ws4 = (float4*)Ws;
        for (int i = threadIdx.x; i < HID * HID / 4; i += 512) Ws4[i] = W4[i];
    }
    __syncthreads();

    int c  = threadIdx.x & 127;
    int rg = threadIdx.x >> 7;                 // 0..3
    int row0 = blockIdx.x * 32 + rg * 8;

    float acc[8];
#pragma unroll
    for (int r = 0; r < 8; ++r) acc[r] = 0.0f;

    for (int k4 = 0; k4 < HID; k4 += 4) {
        float4 xv[8];
#pragma unroll
        for (int r = 0; r < 8; ++r) {
            int row = row0 + r;
            if (row < n) xv[r] = *(const float4*)&X[row * HID + k4];
            else         xv[r] = make_float4(0.f, 0.f, 0.f, 0.f);
        }
#pragma unroll
        for (int dk = 0; dk < 4; ++dk) {
            float w = Ws[(k4 + dk) * HID + c];
#pragma unroll
            for (int r = 0; r < 8; ++r) {
                float xs = (dk == 0) ? xv[r].x : (dk == 1) ? xv[r].y : (dk == 2) ? xv[r].z : xv[r].w;
                acc[r] = fmaf(xs, w, acc[r]);
            }
        }
    }
#pragma unroll
    for (int r = 0; r < 8; ++r) {
        int row = row0 + r;
        if (row < n) Hout[row * HID + c] = acc[r];
    }
}

// ---------------------------------------------------------------------------
// Fused aggregation: wave per node.  out = [relu](sum_in h[src]*dinv[s]*dinv[v]
//                                              + h[v]*dinv[v]^2 + b)
// ---------------------------------------------------------------------------
template <bool RELU>
__global__ void k_gather(const float* __restrict__ Hin, const int* __restrict__ row_start,
                         const int* __restrict__ src_sorted, const float* __restrict__ dinv,
                         const float* __restrict__ bias, float* __restrict__ Aout, int n) {
    int wid  = (blockIdx.x * blockDim.x + threadIdx.x) >> 6;
    int lane = threadIdx.x & 63;
    if (wid >= n) return;
    int v = wid;
    float dv = dinv[v];
    float2 hv = *(const float2*)&Hin[v * HID + 2 * lane];
    float2 acc;
    acc.x = hv.x * dv * dv;
    acc.y = hv.y * dv * dv;
    int e0 = row_start[v], e1 = row_start[v + 1];
    for (int e = e0; e < e1; ++e) {
        int s = src_sorted[e];
        float nrm = dinv[s] * dv;
        float2 hs = *(const float2*)&Hin[s * HID + 2 * lane];
        acc.x = fmaf(hs.x, nrm, acc.x);
        acc.y = fmaf(hs.y, nrm, acc.y);
    }
    float2 bb = *(const float2*)&bias[2 * lane];
    acc.x += bb.x;
    acc.y += bb.y;
    if (RELU) {
        acc.x = fmaxf(acc.x, 0.0f);
        acc.y = fmaxf(acc.y, 0.0f);
    }
    *(float2*)&Aout[v * HID + 2 * lane] = acc;
}

// ---------------------------------------------------------------------------
// Pooling: batch is sorted -> wave accumulates 128-node chunk locally,
// flushes atomics only at graph boundaries.
// ---------------------------------------------------------------------------
__global__ void k_pool(const float* __restrict__ A, const int* __restrict__ batch,
                       float* __restrict__ sums, int n) {
    int wid  = (blockIdx.x * blockDim.x + threadIdx.x) >> 6;
    int lane = threadIdx.x & 63;
    int n0 = wid * 128;
    if (n0 >= n) return;
    int n1 = min(n0 + 128, n);
    float2 s = make_float2(0.f, 0.f);
    int g = batch[n0];
    for (int i = n0; i < n1; ++i) {
        int b = batch[i];
        if (b != g) {
            atomicAdd(&sums[g * HID + 2 * lane + 0], s.x);
            atomicAdd(&sums[g * HID + 2 * lane + 1], s.y);
            s = make_float2(0.f, 0.f);
            g = b;
        }
        float2 hv = *(const float2*)&A[i * HID + 2 * lane];
        s.x += hv.x;
        s.y += hv.y;
    }
    atomicAdd(&sums[g * HID + 2 * lane + 0], s.x);
    atomicAdd(&sums[g * HID + 2 * lane + 1], s.y);
}

__global__ void k_cnt(const int* __restrict__ batch, float* __restrict__ cnt, int n) {
    int i = blockIdx.x * blockDim.x + threadIdx.x;
    if (i < n) atomicAdd(&cnt[batch[i]], 1.0f);
}

// out[g,c] = (sums[g]/max(cnt,1)) . linW[:,c] + linb[c]
__global__ void k_final(const float* __restrict__ sums, const float* __restrict__ cnt,
                        const float* __restrict__ linW, const float* __restrict__ linb,
                        float* __restrict__ out) {
    int idx = blockIdx.x * blockDim.x + threadIdx.x;
    if (idx >= NGRAPH * 2) return;
    int g = idx >> 1, c = idx & 1;
    float inv = 1.0f / fmaxf(cnt[g], 1.0f);
    float a = 0.0f;
    for (int k = 0; k < HID; ++k) a = fmaf(sums[g * HID + k], linW[k * 2 + c], a);
    out[idx] = a * inv + linb[c];
}

// ---------------------------------------------------------------------------

extern "C" void kernel_launch(void* const* d_in, const int* in_sizes, int n_in,
                              void* d_out, int out_size, void* d_ws, size_t ws_size,
                              hipStream_t stream) {
    const float* x    = (const float*)d_in[0];
    const float* W1   = (const float*)d_in[1];
    const float* b1   = (const float*)d_in[2];
    const float* W2   = (const float*)d_in[3];
    const float* b2   = (const float*)d_in[4];
    const float* W3   = (const float*)d_in[5];
    const float* b3   = (const float*)d_in[6];
    const float* W4   = (const float*)d_in[7];
    const float* b4   = (const float*)d_in[8];
    const float* linW = (const float*)d_in[9];
    const float* linb = (const float*)d_in[10];
    const int*   ei   = (const int*)d_in[11];   // [2,E]
    const int*   batch= (const int*)d_in[12];   // [N]
    float* out        = (float*)d_out;

    const int N = in_sizes[0] / 3;
    const int E = in_sizes[11] / 2;

    // Workspace layout (float/int slots of 4 B each)
    float* ws = (float*)d_ws;
    float* dinv       = ws;                            // N floats  (pad to 50176)
    int*   deg_i      = (int*)(ws + 50176);            // N ints
    int*   row_start  = (int*)(ws + 100352);           // N+1 ints
    int*   cursor     = (int*)(ws + 150528);           // N ints
    int*   src_sorted = (int*)(ws + 200704);           // E ints (pad to 800768)
    float* Hbuf       = ws + 800768;                   // N*128
    float* Act        = ws + 7200768;                  // N*128
    float* Sums       = ws + 13600768;                 // 512*128
    float* Cnt        = ws + 13666304;                 // 512

    const int B = 256;

    // --- CSR setup ---
    hipMemsetAsync(deg_i, 0, N * sizeof(int), stream);
    hipMemsetAsync(Sums, 0, (NGRAPH * HID + NGRAPH) * sizeof(float), stream);  // Sums+Cnt contiguous
    k_count<<<(E + B - 1) / B, B, 0, stream>>>(ei, deg_i, E);
    k_dinv<<<(N + B - 1) / B, B, 0, stream>>>(deg_i, dinv, N);
    k_scan<<<1, 1024, 0, stream>>>(deg_i, row_start, cursor, N);
    k_fill<<<(E + B - 1) / B, B, 0, stream>>>(ei, cursor, src_sorted, E);

    const int gatherBlocks = (N + 3) / 4;          // 4 waves per 256-thread block
    const int gemmBlocks   = (N + 31) / 32;

    // --- Layer 1 ---
    k_gemm3<<<(N * HID + B - 1) / B, B, 0, stream>>>(x, W1, Hbuf, N);
    k_gather<true><<<gatherBlocks, B, 0, stream>>>(Hbuf, row_start, src_sorted, dinv, b1, Act, N);
    // --- Layer 2 ---
    k_gemm128<<<gemmBlocks, 512, 0, stream>>>(Act, W2, Hbuf, N);
    k_gather<true><<<gatherBlocks, B, 0, stream>>>(Hbuf, row_start, src_sorted, dinv, b2, Act, N);
    // --- Layer 3 ---
    k_gemm128<<<gemmBlocks, 512, 0, stream>>>(Act, W3, Hbuf, N);
    k_gather<true><<<gatherBlocks, B, 0, stream>>>(Hbuf, row_start, src_sorted, dinv, b3, Act, N);
    // --- Layer 4 (no relu) ---
    k_gemm128<<<gemmBlocks, 512, 0, stream>>>(Act, W4, Hbuf, N);
    k_gather<false><<<gatherBlocks, B, 0, stream>>>(Hbuf, row_start, src_sorted, dinv, b4, Act, N);

    // --- Pool + head ---
    const int poolWaves = (N + 127) / 128;
    k_pool<<<(poolWaves + 3) / 4, B, 0, stream>>>(Act, batch, Sums, N);
    k_cnt<<<(N + B - 1) / B, B, 0, stream>>>(batch, Cnt, N);
    k_final<<<(NGRAPH * 2 + B - 1) / B, B, 0, stream>>>(Sums, Cnt, linW, linb, out);
}

// Round 2
// 693.397 us; speedup vs baseline: 10.3528x; 10.3528x over previous
//
#include <hip/hip_runtime.h>
#include <hip/hip_bf16.h>

// Problem constants (from reference)
#define HID 128
#define NGRAPH 512

// ---------------------------------------------------------------------------
// Setup kernels: degree count, rsqrt, scan (CSR row_start), CSR fill
// ---------------------------------------------------------------------------

__global__ void k_count(const int* __restrict__ ei, int* __restrict__ deg, int E) {
    int e = blockIdx.x * blockDim.x + threadIdx.x;
    if (e < E) atomicAdd(&deg[ei[E + e]], 1);  // dst row
}

__global__ void k_dinv(const int* __restrict__ deg, float* __restrict__ dinv, int n) {
    int i = blockIdx.x * blockDim.x + threadIdx.x;
    if (i < n) dinv[i] = rsqrtf((float)deg[i] + 1.0f);  // +1 self-loop
}

// Single-block scan, 8 values/thread: exclusive prefix of deg -> row_start, cursor
__global__ void k_scan(const int* __restrict__ deg, int* __restrict__ row_start,
                       int* __restrict__ cursor, int n) {
    __shared__ int sm[1024];
    __shared__ int running_s;
    int tid = threadIdx.x;
    if (tid == 0) running_s = 0;
    __syncthreads();
    const int VPT = 8;
    for (int base = 0; base < n; base += 1024 * VPT) {
        int i0 = base + tid * VPT;
        int v[VPT];
        int lsum = 0;
#pragma unroll
        for (int j = 0; j < VPT; ++j) {
            int i = i0 + j;
            v[j] = (i < n) ? deg[i] : 0;
            lsum += v[j];
        }
        sm[tid] = lsum;
        __syncthreads();
#pragma unroll
        for (int off = 1; off < 1024; off <<= 1) {
            int t = (tid >= off) ? sm[tid - off] : 0;
            __syncthreads();
            sm[tid] += t;
            __syncthreads();
        }
        int r = running_s + sm[tid] - lsum;  // exclusive prefix for this thread's chunk
        int total = sm[1023];
#pragma unroll
        for (int j = 0; j < VPT; ++j) {
            int i = i0 + j;
            if (i < n) { row_start[i] = r; cursor[i] = r; }
            r += v[j];
        }
        __syncthreads();
        if (tid == 0) running_s += total;
        __syncthreads();
    }
    if (tid == 0) row_start[n] = running_s;
}

__global__ void k_fill(const int* __restrict__ ei, int* __restrict__ cursor,
                       int* __restrict__ src_sorted, int E) {
    int e = blockIdx.x * blockDim.x + threadIdx.x;
    if (e < E) {
        int s = ei[e];
        int d = ei[E + e];
        int pos = atomicAdd(&cursor[d], 1);
        src_sorted[pos] = s;
    }
}

// ---------------------------------------------------------------------------
// GEMMs
// ---------------------------------------------------------------------------

// Layer-1: x[N,3] @ W[3,128] -> H[N,128]   (thread per output element)
__global__ void k_gemm3(const float* __restrict__ X, const float* __restrict__ W,
                        float* __restrict__ Hout, int n) {
    int idx = blockIdx.x * blockDim.x + threadIdx.x;
    if (idx >= n * HID) return;
    int i = idx >> 7, c = idx & 127;
    float x0 = X[i * 3 + 0], x1 = X[i * 3 + 1], x2 = X[i * 3 + 2];
    Hout[idx] = x0 * W[c] + x1 * W[HID + c] + x2 * W[2 * HID + c];
}

// [Npad,128] @ [128,128] -> [Npad,128].  256 threads/block, 32 rows/block.
// Thread = 4 rows x 4 cols (float4).  No LDS, no bounds checks (padded rows).
// W loads: lanes share 512B segments -> L1/L2 broadcast.  ~50 VGPR, no spill.
__global__ __launch_bounds__(256) void k_gemm128(const float* __restrict__ X,
                                                 const float* __restrict__ W,
                                                 float* __restrict__ Hout) {
    int cg = threadIdx.x & 31;     // float4 column index (cols cg*4 .. cg*4+3)
    int rg = threadIdx.x >> 5;     // 0..7 row group
    long row0 = (long)blockIdx.x * 32 + rg * 4;
    const float4* X4 = (const float4*)(X + row0 * HID);  // X4[r*32 + k4]
    const float4* W4 = (const float4*)W;                 // W4[k*32 + c4]

    float4 acc[4];
#pragma unroll
    for (int r = 0; r < 4; ++r) acc[r] = make_float4(0.f, 0.f, 0.f, 0.f);

#pragma unroll 4
    for (int k4 = 0; k4 < 32; ++k4) {
        float4 x[4];
#pragma unroll
        for (int r = 0; r < 4; ++r) x[r] = X4[r * 32 + k4];
#pragma unroll
        for (int dk = 0; dk < 4; ++dk) {
            float4 w = W4[(k4 * 4 + dk) * 32 + cg];
#pragma unroll
            for (int r = 0; r < 4; ++r) {
                float xs = (dk == 0) ? x[r].x : (dk == 1) ? x[r].y
                         : (dk == 2) ? x[r].z : x[r].w;
                acc[r].x = fmaf(xs, w.x, acc[r].x);
                acc[r].y = fmaf(xs, w.y, acc[r].y);
                acc[r].z = fmaf(xs, w.z, acc[r].z);
                acc[r].w = fmaf(xs, w.w, acc[r].w);
            }
        }
    }

    float4* O4 = (float4*)(Hout + row0 * HID);
#pragma unroll
    for (int r = 0; r < 4; ++r) O4[r * 32 + cg] = acc[r];
}

// ---------------------------------------------------------------------------
// Fused aggregation: wave per node.  out = [relu](sum_in h[src]*dinv[s]*dinv[v]
//                                              + h[v]*dinv[v]^2 + b)
// ---------------------------------------------------------------------------
template <bool RELU>
__global__ void k_gather(const float* __restrict__ Hin, const int* __restrict__ row_start,
                         const int* __restrict__ src_sorted, const float* __restrict__ dinv,
                         const float* __restrict__ bias, float* __restrict__ Aout, int n) {
    int wid  = (blockIdx.x * blockDim.x + threadIdx.x) >> 6;
    int lane = threadIdx.x & 63;
    if (wid >= n) return;
    int v = wid;
    float dv = dinv[v];
    float2 hv = *(const float2*)&Hin[v * HID + 2 * lane];
    float2 acc;
    acc.x = hv.x * dv * dv;
    acc.y = hv.y * dv * dv;
    int e0 = row_start[v], e1 = row_start[v + 1];
    for (int e = e0; e < e1; ++e) {
        int s = src_sorted[e];
        float nrm = dinv[s] * dv;
        float2 hs = *(const float2*)&Hin[s * HID + 2 * lane];
        acc.x = fmaf(hs.x, nrm, acc.x);
        acc.y = fmaf(hs.y, nrm, acc.y);
    }
    float2 bb = *(const float2*)&bias[2 * lane];
    acc.x += bb.x;
    acc.y += bb.y;
    if (RELU) {
        acc.x = fmaxf(acc.x, 0.0f);
        acc.y = fmaxf(acc.y, 0.0f);
    }
    *(float2*)&Aout[v * HID + 2 * lane] = acc;
}

// ---------------------------------------------------------------------------
// Pooling: batch is sorted -> wave accumulates 128-node chunk locally,
// flushes atomics only at graph boundaries.
// ---------------------------------------------------------------------------
__global__ void k_pool(const float* __restrict__ A, const int* __restrict__ batch,
                       float* __restrict__ sums, int n) {
    int wid  = (blockIdx.x * blockDim.x + threadIdx.x) >> 6;
    int lane = threadIdx.x & 63;
    int n0 = wid * 128;
    if (n0 >= n) return;
    int n1 = min(n0 + 128, n);
    float2 s = make_float2(0.f, 0.f);
    int g = batch[n0];
    for (int i = n0; i < n1; ++i) {
        int b = batch[i];
        if (b != g) {
            atomicAdd(&sums[g * HID + 2 * lane + 0], s.x);
            atomicAdd(&sums[g * HID + 2 * lane + 1], s.y);
            s = make_float2(0.f, 0.f);
            g = b;
        }
        float2 hv = *(const float2*)&A[i * HID + 2 * lane];
        s.x += hv.x;
        s.y += hv.y;
    }
    atomicAdd(&sums[g * HID + 2 * lane + 0], s.x);
    atomicAdd(&sums[g * HID + 2 * lane + 1], s.y);
}

__global__ void k_cnt(const int* __restrict__ batch, float* __restrict__ cnt, int n) {
    int i = blockIdx.x * blockDim.x + threadIdx.x;
    if (i < n) atomicAdd(&cnt[batch[i]], 1.0f);
}

// out[g,c] = (sums[g]/max(cnt,1)) . linW[:,c] + linb[c]
__global__ void k_final(const float* __restrict__ sums, const float* __restrict__ cnt,
                        const float* __restrict__ linW, const float* __restrict__ linb,
                        float* __restrict__ out) {
    int idx = blockIdx.x * blockDim.x + threadIdx.x;
    if (idx >= NGRAPH * 2) return;
    int g = idx >> 1, c = idx & 1;
    float inv = 1.0f / fmaxf(cnt[g], 1.0f);
    float a = 0.0f;
    for (int k = 0; k < HID; ++k) a = fmaf(sums[g * HID + k], linW[k * 2 + c], a);
    out[idx] = a * inv + linb[c];
}

// ---------------------------------------------------------------------------

extern "C" void kernel_launch(void* const* d_in, const int* in_sizes, int n_in,
                              void* d_out, int out_size, void* d_ws, size_t ws_size,
                              hipStream_t stream) {
    const float* x    = (const float*)d_in[0];
    const float* W1   = (const float*)d_in[1];
    const float* b1   = (const float*)d_in[2];
    const float* W2   = (const float*)d_in[3];
    const float* b2   = (const float*)d_in[4];
    const float* W3   = (const float*)d_in[5];
    const float* b3   = (const float*)d_in[6];
    const float* W4   = (const float*)d_in[7];
    const float* b4   = (const float*)d_in[8];
    const float* linW = (const float*)d_in[9];
    const float* linb = (const float*)d_in[10];
    const int*   ei   = (const int*)d_in[11];   // [2,E]
    const int*   batch= (const int*)d_in[12];   // [N]
    float* out        = (float*)d_out;

    const int N = in_sizes[0] / 3;
    const int E = in_sizes[11] / 2;
    const int NPAD = ((N + 31) / 32) * 32;      // row-padded for bound-check-free GEMM

    // Workspace layout (4-B slots)
    float* ws = (float*)d_ws;
    float* dinv       = ws;                            // N floats  (pad to 50176)
    int*   deg_i      = (int*)(ws + 50176);            // N ints
    int*   row_start  = (int*)(ws + 100352);           // N+1 ints
    int*   cursor     = (int*)(ws + 150528);           // N ints
    int*   src_sorted = (int*)(ws + 200704);           // E ints (pad to 600064)
    float* Hbuf       = ws + 800768;                   // NPAD*128
    float* Act        = Hbuf + (size_t)NPAD * HID;     // NPAD*128
    float* Sums       = Act + (size_t)NPAD * HID;      // 512*128
    float* Cnt        = Sums + NGRAPH * HID;           // 512

    const int B = 256;

    // --- CSR setup ---
    hipMemsetAsync(deg_i, 0, N * sizeof(int), stream);
    hipMemsetAsync(Sums, 0, (NGRAPH * HID + NGRAPH) * sizeof(float), stream);  // Sums+Cnt contiguous
    k_count<<<(E + B - 1) / B, B, 0, stream>>>(ei, deg_i, E);
    k_dinv<<<(N + B - 1) / B, B, 0, stream>>>(deg_i, dinv, N);
    k_scan<<<1, 1024, 0, stream>>>(deg_i, row_start, cursor, N);
    k_fill<<<(E + B - 1) / B, B, 0, stream>>>(ei, cursor, src_sorted, E);

    const int gatherBlocks = (N + 3) / 4;          // 4 waves per 256-thread block
    const int gemmBlocks   = NPAD / 32;

    // --- Layer 1 ---
    k_gemm3<<<(N * HID + B - 1) / B, B, 0, stream>>>(x, W1, Hbuf, N);
    k_gather<true><<<gatherBlocks, B, 0, stream>>>(Hbuf, row_start, src_sorted, dinv, b1, Act, N);
    // --- Layer 2 ---
    k_gemm128<<<gemmBlocks, B, 0, stream>>>(Act, W2, Hbuf);
    k_gather<true><<<gatherBlocks, B, 0, stream>>>(Hbuf, row_start, src_sorted, dinv, b2, Act, N);
    // --- Layer 3 ---
    k_gemm128<<<gemmBlocks, B, 0, stream>>>(Act, W3, Hbuf);
    k_gather<true><<<gatherBlocks, B, 0, stream>>>(Hbuf, row_start, src_sorted, dinv, b3, Act, N);
    // --- Layer 4 (no relu) ---
    k_gemm128<<<gemmBlocks, B, 0, stream>>>(Act, W4, Hbuf);
    k_gather<false><<<gatherBlocks, B, 0, stream>>>(Hbuf, row_start, src_sorted, dinv, b4, Act, N);

    // --- Pool + head ---
    const int poolWaves = (N + 127) / 128;
    k_pool<<<(poolWaves + 3) / 4, B, 0, stream>>>(Act, batch, Sums, N);
    k_cnt<<<(N + B - 1) / B, B, 0, stream>>>(batch, Cnt, N);
    k_final<<<(NGRAPH * 2 + B - 1) / B, B, 0, stream>>>(Sums, Cnt, linW, linb, out);
}

// Round 3
// 479.433 us; speedup vs baseline: 14.9730x; 1.4463x over previous
//
#include <hip/hip_runtime.h>
#include <hip/hip_bf16.h>

#define HID 128
#define NGRAPH 512

// ---------------------------------------------------------------------------
// CSR setup
// ---------------------------------------------------------------------------

__global__ void k_count(const int* __restrict__ ei, int* __restrict__ deg, int E) {
    int e = blockIdx.x * blockDim.x + threadIdx.x;
    if (e < E) atomicAdd(&deg[ei[E + e]], 1);  // dst row
}

// Per-block (1024-elem) sums of deg
__global__ void k_bsum(const int* __restrict__ deg, int* __restrict__ bsum, int n) {
    int i = blockIdx.x * 1024 + threadIdx.x;
    int v = (i < n) ? deg[i] : 0;
#pragma unroll
    for (int off = 32; off; off >>= 1) v += __shfl_down(v, off);
    __shared__ int ws[16];
    int wid = threadIdx.x >> 6, lane = threadIdx.x & 63;
    if (lane == 0) ws[wid] = v;
    __syncthreads();
    if (threadIdx.x == 0) {
        int s = 0;
#pragma unroll
        for (int w = 0; w < 16; ++w) s += ws[w];
        bsum[blockIdx.x] = s;
    }
}

// Per-block rescan: exclusive prefix -> row_start, cursor; also dinv = rsqrt(deg+1)
__global__ void k_scan2(const int* __restrict__ deg, const int* __restrict__ bsum,
                        int* __restrict__ row_start, int* __restrict__ cursor,
                        float* __restrict__ dinv, int n, int nblocks) {
    __shared__ int s_off, s_tot;
    __shared__ int ws[16];
    if (threadIdx.x < 64) {                      // block offset = sum bsum[0..blockIdx)
        int v = ((int)threadIdx.x < blockIdx.x) ? bsum[threadIdx.x] : 0;
#pragma unroll
        for (int off = 32; off; off >>= 1) v += __shfl_down(v, off);
        if (threadIdx.x == 0) s_off = v;
    } else if (threadIdx.x < 128 && blockIdx.x == 0) {  // grand total (block 0 only)
        int l = threadIdx.x - 64;
        int v = (l < nblocks) ? bsum[l] : 0;
#pragma unroll
        for (int off = 32; off; off >>= 1) v += __shfl_down(v, off);
        if (l == 0) s_tot = v;
    }
    int i = blockIdx.x * 1024 + threadIdx.x;
    int v = (i < n) ? deg[i] : 0;
    if (i < n) dinv[i] = rsqrtf((float)v + 1.0f);
    // inclusive wave scan
    int x = v;
    int lane = threadIdx.x & 63, wid = threadIdx.x >> 6;
#pragma unroll
    for (int off = 1; off < 64; off <<= 1) {
        int t = __shfl_up(x, off);
        if (lane >= off) x += t;
    }
    if (lane == 63) ws[wid] = x;
    __syncthreads();
    int wo = 0;
    for (int w = 0; w < wid; ++w) wo += ws[w];
    int excl = s_off + wo + x - v;
    if (i < n) { row_start[i] = excl; cursor[i] = excl; }
    if (blockIdx.x == 0 && threadIdx.x == 0) row_start[n] = s_tot;
}

__global__ void k_fill(const int* __restrict__ ei, int* __restrict__ cursor,
                       int* __restrict__ src_sorted, int E) {
    int e = blockIdx.x * blockDim.x + threadIdx.x;
    if (e < E) {
        int s = ei[e];
        int d = ei[E + e];
        int pos = atomicAdd(&cursor[d], 1);
        src_sorted[pos] = s;
    }
}

// W4' = W4 @ linW  [128,2];  b4' = b4 @ linW + linb  [2]
__global__ void k_foldW(const float* __restrict__ W4, const float* __restrict__ linW,
                        const float* __restrict__ b4, const float* __restrict__ linb,
                        float* __restrict__ W4p, float* __restrict__ b4p) {
    int idx = threadIdx.x;                 // 256 threads
    int k = idx >> 1, c = idx & 1;
    float a = 0.0f;
    for (int j = 0; j < HID; ++j) a = fmaf(W4[k * 2 * HID / 2 + j], linW[j * 2 + c], a);
    // note: W4 is [128,128]; row k is W4[k*128 + j]
    W4p[idx] = a;
    if (idx < 2) {
        float b = 0.0f;
        for (int j = 0; j < HID; ++j) b = fmaf(b4[j], linW[j * 2 + idx], b);
        b4p[idx] = b + linb[idx];
    }
}

// ---------------------------------------------------------------------------
// Layer 1 (reordered):  Xa = A_hat x  (3-wide), then Act = relu(Xa W1 + b1)
// ---------------------------------------------------------------------------

__global__ void k_gather3(const float* __restrict__ x, const int* __restrict__ row_start,
                          const int* __restrict__ src_sorted, const float* __restrict__ dinv,
                          float* __restrict__ xa, int n) {
    int v = blockIdx.x * blockDim.x + threadIdx.x;
    if (v >= n) return;
    float dv = dinv[v];
    float a0 = x[v * 3 + 0] * dv * dv;
    float a1 = x[v * 3 + 1] * dv * dv;
    float a2 = x[v * 3 + 2] * dv * dv;
    int e1 = row_start[v + 1];
    for (int e = row_start[v]; e < e1; ++e) {
        int s = src_sorted[e];
        float nrm = dinv[s] * dv;
        a0 = fmaf(x[s * 3 + 0], nrm, a0);
        a1 = fmaf(x[s * 3 + 1], nrm, a1);
        a2 = fmaf(x[s * 3 + 2], nrm, a2);
    }
    xa[v * 4 + 0] = a0;
    xa[v * 4 + 1] = a1;
    xa[v * 4 + 2] = a2;
}

// Act[v,c] = relu(xa[v,:3] . W1[:,c] + b1[c]);  zero padding rows
__global__ void k_feat(const float* __restrict__ xa, const float* __restrict__ W1,
                       const float* __restrict__ b1, float* __restrict__ Act, int n) {
    int idx = blockIdx.x * blockDim.x + threadIdx.x;
    int v = idx >> 7, c = idx & 127;
    float r = 0.0f;
    if (v < n) {
        r = fmaf(xa[v * 4 + 0], W1[c],
            fmaf(xa[v * 4 + 1], W1[HID + c],
            fmaf(xa[v * 4 + 2], W1[2 * HID + c], b1[c])));
        r = fmaxf(r, 0.0f);
    }
    Act[idx] = r;
}

// ---------------------------------------------------------------------------
// [Npad,128] @ [128,128] -> [Npad,128].  256 thr, 32 rows/block, 4x4 float4 tile.
// ---------------------------------------------------------------------------
__global__ __launch_bounds__(256) void k_gemm128(const float* __restrict__ X,
                                                 const float* __restrict__ W,
                                                 float* __restrict__ Hout) {
    int cg = threadIdx.x & 31;
    int rg = threadIdx.x >> 5;
    long row0 = (long)blockIdx.x * 32 + rg * 4;
    const float4* X4 = (const float4*)(X + row0 * HID);
    const float4* W4 = (const float4*)W;

    float4 acc[4];
#pragma unroll
    for (int r = 0; r < 4; ++r) acc[r] = make_float4(0.f, 0.f, 0.f, 0.f);

#pragma unroll 4
    for (int k4 = 0; k4 < 32; ++k4) {
        float4 x[4];
#pragma unroll
        for (int r = 0; r < 4; ++r) x[r] = X4[r * 32 + k4];
#pragma unroll
        for (int dk = 0; dk < 4; ++dk) {
            float4 w = W4[(k4 * 4 + dk) * 32 + cg];
#pragma unroll
            for (int r = 0; r < 4; ++r) {
                float xs = (dk == 0) ? x[r].x : (dk == 1) ? x[r].y
                         : (dk == 2) ? x[r].z : x[r].w;
                acc[r].x = fmaf(xs, w.x, acc[r].x);
                acc[r].y = fmaf(xs, w.y, acc[r].y);
                acc[r].z = fmaf(xs, w.z, acc[r].z);
                acc[r].w = fmaf(xs, w.w, acc[r].w);
            }
        }
    }

    float4* O4 = (float4*)(Hout + row0 * HID);
#pragma unroll
    for (int r = 0; r < 4; ++r) O4[r * 32 + cg] = acc[r];
}

// ---------------------------------------------------------------------------
// Fused aggregation: wave per node
// ---------------------------------------------------------------------------
template <bool RELU, bool BIAS>
__global__ void k_gather(const float* __restrict__ Hin, const int* __restrict__ row_start,
                         const int* __restrict__ src_sorted, const float* __restrict__ dinv,
                         const float* __restrict__ bias, float* __restrict__ Aout, int n) {
    int wid  = (blockIdx.x * blockDim.x + threadIdx.x) >> 6;
    int lane = threadIdx.x & 63;
    if (wid >= n) return;
    int v = wid;
    float dv = dinv[v];
    float2 hv = *(const float2*)&Hin[v * HID + 2 * lane];
    float2 acc;
    acc.x = hv.x * dv * dv;
    acc.y = hv.y * dv * dv;
    int e0 = row_start[v], e1 = row_start[v + 1];
    for (int e = e0; e < e1; ++e) {
        int s = src_sorted[e];
        float nrm = dinv[s] * dv;
        float2 hs = *(const float2*)&Hin[s * HID + 2 * lane];
        acc.x = fmaf(hs.x, nrm, acc.x);
        acc.y = fmaf(hs.y, nrm, acc.y);
    }
    if (BIAS) {
        float2 bb = *(const float2*)&bias[2 * lane];
        acc.x += bb.x;
        acc.y += bb.y;
    }
    if (RELU) {
        acc.x = fmaxf(acc.x, 0.0f);
        acc.y = fmaxf(acc.y, 0.0f);
    }
    *(float2*)&Aout[v * HID + 2 * lane] = acc;
}

// ---------------------------------------------------------------------------
// Pool (sorted batch, chunked, fused node-count)
// ---------------------------------------------------------------------------
__global__ void k_pool(const float* __restrict__ A, const int* __restrict__ batch,
                       float* __restrict__ sums, float* __restrict__ cnt, int n) {
    int wid  = (blockIdx.x * blockDim.x + threadIdx.x) >> 6;
    int lane = threadIdx.x & 63;
    int n0 = wid * 128;
    if (n0 >= n) return;
    int n1 = min(n0 + 128, n);
    float2 s = make_float2(0.f, 0.f);
    int run = 0;
    int g = batch[n0];
    for (int i = n0; i < n1; ++i) {
        int b = batch[i];
        if (b != g) {
            atomicAdd(&sums[g * HID + 2 * lane + 0], s.x);
            atomicAdd(&sums[g * HID + 2 * lane + 1], s.y);
            if (lane == 0) atomicAdd(&cnt[g], (float)run);
            s = make_float2(0.f, 0.f);
            run = 0;
            g = b;
        }
        float2 hv = *(const float2*)&A[i * HID + 2 * lane];
        s.x += hv.x;
        s.y += hv.y;
        ++run;
    }
    atomicAdd(&sums[g * HID + 2 * lane + 0], s.x);
    atomicAdd(&sums[g * HID + 2 * lane + 1], s.y);
    if (lane == 0) atomicAdd(&cnt[g], (float)run);
}

// out[g,c] = (sums[g] . W4p[:,c]) / max(cnt,1) + b4p[c]
__global__ void k_final(const float* __restrict__ sums, const float* __restrict__ cnt,
                        const float* __restrict__ W4p, const float* __restrict__ b4p,
                        float* __restrict__ out) {
    int idx = blockIdx.x * blockDim.x + threadIdx.x;
    if (idx >= NGRAPH * 2) return;
    int g = idx >> 1, c = idx & 1;
    float a = 0.0f;
    for (int k = 0; k < HID; ++k) a = fmaf(sums[g * HID + k], W4p[k * 2 + c], a);
    out[idx] = a / fmaxf(cnt[g], 1.0f) + b4p[c];
}

// ---------------------------------------------------------------------------

extern "C" void kernel_launch(void* const* d_in, const int* in_sizes, int n_in,
                              void* d_out, int out_size, void* d_ws, size_t ws_size,
                              hipStream_t stream) {
    const float* x    = (const float*)d_in[0];
    const float* W1   = (const float*)d_in[1];
    const float* b1   = (const float*)d_in[2];
    const float* W2   = (const float*)d_in[3];
    const float* b2   = (const float*)d_in[4];
    const float* W3   = (const float*)d_in[5];
    const float* b3   = (const float*)d_in[6];
    const float* W4   = (const float*)d_in[7];
    const float* b4   = (const float*)d_in[8];
    const float* linW = (const float*)d_in[9];
    const float* linb = (const float*)d_in[10];
    const int*   ei   = (const int*)d_in[11];   // [2,E]
    const int*   batch= (const int*)d_in[12];   // [N]
    float* out        = (float*)d_out;

    const int N = in_sizes[0] / 3;
    const int E = in_sizes[11] / 2;
    const int NPAD = ((N + 31) / 32) * 32;
    const int NB1024 = (N + 1023) / 1024;

    // Workspace layout (4-B slots)
    float* ws = (float*)d_ws;
    float* dinv       = ws;                            // 50176
    int*   deg_i      = (int*)(ws + 50176);            // 50176
    int*   row_start  = (int*)(ws + 100352);           // 50432 (N+1)
    int*   cursor     = (int*)(ws + 150784);           // 50176
    int*   bsum       = (int*)(ws + 200960);           // 64
    float* W4p        = ws + 201024;                   // 256
    float* b4p        = ws + 201280;                   // 64 (2 used)
    int*   src_sorted = (int*)(ws + 201344);           // 600064
    float* Xa         = ws + 801408;                   // N*4
    float* Hbuf       = ws + 1002112;                  // NPAD*128
    float* Act        = Hbuf + (size_t)NPAD * HID;     // NPAD*128
    float* Sums       = Act + (size_t)NPAD * HID;      // 512*128
    float* Cnt        = Sums + NGRAPH * HID;           // 512

    const int B = 256;

    // --- CSR setup ---
    hipMemsetAsync(deg_i, 0, N * sizeof(int), stream);
    hipMemsetAsync(Sums, 0, (NGRAPH * HID + NGRAPH) * sizeof(float), stream);
    k_count<<<(E + B - 1) / B, B, 0, stream>>>(ei, deg_i, E);
    k_bsum<<<NB1024, 1024, 0, stream>>>(deg_i, bsum, N);
    k_scan2<<<NB1024, 1024, 0, stream>>>(deg_i, bsum, row_start, cursor, dinv, N, NB1024);
    k_fill<<<(E + B - 1) / B, B, 0, stream>>>(ei, cursor, src_sorted, E);
    k_foldW<<<1, 256, 0, stream>>>(W4, linW, b4, linb, W4p, b4p);

    const int gatherBlocks = (N + 3) / 4;      // 4 waves / 256-thr block
    const int gemmBlocks   = NPAD / 32;

    // --- Layer 1 (reordered) ---
    k_gather3<<<(N + B - 1) / B, B, 0, stream>>>(x, row_start, src_sorted, dinv, Xa, N);
    k_feat<<<(NPAD * HID) / B, B, 0, stream>>>(Xa, W1, b1, Act, N);
    // --- Layer 2 ---
    k_gemm128<<<gemmBlocks, B, 0, stream>>>(Act, W2, Hbuf);
    k_gather<true, true><<<gatherBlocks, B, 0, stream>>>(Hbuf, row_start, src_sorted, dinv, b2, Act, N);
    // --- Layer 3 ---
    k_gemm128<<<gemmBlocks, B, 0, stream>>>(Act, W3, Hbuf);
    k_gather<true, true><<<gatherBlocks, B, 0, stream>>>(Hbuf, row_start, src_sorted, dinv, b3, Act, N);
    // --- Layer 4 (folded into head): Agg4 = A_hat Act3 ---
    k_gather<false, false><<<gatherBlocks, B, 0, stream>>>(Act, row_start, src_sorted, dinv, nullptr, Hbuf, N);

    // --- Pool + head ---
    const int poolWaves = (N + 127) / 128;
    k_pool<<<(poolWaves + 3) / 4, B, 0, stream>>>(Hbuf, batch, Sums, Cnt, N);
    k_final<<<(NGRAPH * 2 + B - 1) / B, B, 0, stream>>>(Sums, Cnt, W4p, b4p, out);
}

// Round 4
// 363.140 us; speedup vs baseline: 19.7681x; 1.3202x over previous
//
#include <hip/hip_runtime.h>
#include <hip/hip_bf16.h>

#define HID 128
#define NGRAPH 512

// ---------------------------------------------------------------------------
// CSR setup
// ---------------------------------------------------------------------------

__global__ void k_count(const int* __restrict__ ei, int* __restrict__ deg, int E) {
    int e = blockIdx.x * blockDim.x + threadIdx.x;
    if (e < E) atomicAdd(&deg[ei[E + e]], 1);  // dst row
}

// Per-block (1024-elem) sums of deg
__global__ void k_bsum(const int* __restrict__ deg, int* __restrict__ bsum, int n) {
    int i = blockIdx.x * 1024 + threadIdx.x;
    int v = (i < n) ? deg[i] : 0;
#pragma unroll
    for (int off = 32; off; off >>= 1) v += __shfl_down(v, off);
    __shared__ int ws[16];
    int wid = threadIdx.x >> 6, lane = threadIdx.x & 63;
    if (lane == 0) ws[wid] = v;
    __syncthreads();
    if (threadIdx.x == 0) {
        int s = 0;
#pragma unroll
        for (int w = 0; w < 16; ++w) s += ws[w];
        bsum[blockIdx.x] = s;
    }
}

// Per-block rescan -> row_start, cursor; also dinv = rsqrt(deg+1)
__global__ void k_scan2(const int* __restrict__ deg, const int* __restrict__ bsum,
                        int* __restrict__ row_start, int* __restrict__ cursor,
                        float* __restrict__ dinv, int n, int nblocks) {
    __shared__ int s_off, s_tot;
    __shared__ int ws[16];
    if (threadIdx.x < 64) {
        int v = ((int)threadIdx.x < blockIdx.x) ? bsum[threadIdx.x] : 0;
#pragma unroll
        for (int off = 32; off; off >>= 1) v += __shfl_down(v, off);
        if (threadIdx.x == 0) s_off = v;
    } else if (threadIdx.x < 128 && blockIdx.x == 0) {
        int l = threadIdx.x - 64;
        int v = (l < nblocks) ? bsum[l] : 0;
#pragma unroll
        for (int off = 32; off; off >>= 1) v += __shfl_down(v, off);
        if (l == 0) s_tot = v;
    }
    int i = blockIdx.x * 1024 + threadIdx.x;
    int v = (i < n) ? deg[i] : 0;
    if (i < n) dinv[i] = rsqrtf((float)v + 1.0f);
    int x = v;
    int lane = threadIdx.x & 63, wid = threadIdx.x >> 6;
#pragma unroll
    for (int off = 1; off < 64; off <<= 1) {
        int t = __shfl_up(x, off);
        if (lane >= off) x += t;
    }
    if (lane == 63) ws[wid] = x;
    __syncthreads();
    int wo = 0;
    for (int w = 0; w < wid; ++w) wo += ws[w];
    int excl = s_off + wo + x - v;
    if (i < n) { row_start[i] = excl; cursor[i] = excl; }
    if (blockIdx.x == 0 && threadIdx.x == 0) row_start[n] = s_tot;
}

__global__ void k_fill(const int* __restrict__ ei, int* __restrict__ cursor,
                       int* __restrict__ src_sorted, int E) {
    int e = blockIdx.x * blockDim.x + threadIdx.x;
    if (e < E) {
        int s = ei[e];
        int d = ei[E + e];
        int pos = atomicAdd(&cursor[d], 1);
        src_sorted[pos] = s;
    }
}

// W4p = W4 @ linW  [128,2];  b4p = b4 @ linW + linb  [2]
__global__ void k_foldW(const float* __restrict__ W4, const float* __restrict__ linW,
                        const float* __restrict__ b4, const float* __restrict__ linb,
                        float* __restrict__ W4p, float* __restrict__ b4p) {
    int idx = threadIdx.x;                 // 256 threads
    int k = idx >> 1, c = idx & 1;
    float a = 0.0f;
    for (int j = 0; j < HID; ++j) a = fmaf(W4[k * HID + j], linW[j * 2 + c], a);
    W4p[idx] = a;
    if (idx < 2) {
        float b = 0.0f;
        for (int j = 0; j < HID; ++j) b = fmaf(b4[j], linW[j * 2 + idx], b);
        b4p[idx] = b + linb[idx];
    }
}

// ---------------------------------------------------------------------------
// Layer 1 (reordered):  Xa = A_hat x  (3-wide), then Act = relu(Xa W1 + b1)
// ---------------------------------------------------------------------------

__global__ void k_gather3(const float* __restrict__ x, const int* __restrict__ row_start,
                          const int* __restrict__ src_sorted, const float* __restrict__ dinv,
                          float* __restrict__ xa, int n) {
    int v = blockIdx.x * blockDim.x + threadIdx.x;
    if (v >= n) return;
    float dv = dinv[v];
    float a0 = x[v * 3 + 0] * dv * dv;
    float a1 = x[v * 3 + 1] * dv * dv;
    float a2 = x[v * 3 + 2] * dv * dv;
    int e1 = row_start[v + 1];
    int e = row_start[v];
    for (; e + 4 <= e1; e += 4) {
        int s0 = src_sorted[e + 0], s1 = src_sorted[e + 1];
        int s2 = src_sorted[e + 2], s3 = src_sorted[e + 3];
        float w0 = dinv[s0] * dv, w1 = dinv[s1] * dv;
        float w2 = dinv[s2] * dv, w3 = dinv[s3] * dv;
        a0 = fmaf(x[s0 * 3 + 0], w0, a0); a1 = fmaf(x[s0 * 3 + 1], w0, a1); a2 = fmaf(x[s0 * 3 + 2], w0, a2);
        a0 = fmaf(x[s1 * 3 + 0], w1, a0); a1 = fmaf(x[s1 * 3 + 1], w1, a1); a2 = fmaf(x[s1 * 3 + 2], w1, a2);
        a0 = fmaf(x[s2 * 3 + 0], w2, a0); a1 = fmaf(x[s2 * 3 + 1], w2, a1); a2 = fmaf(x[s2 * 3 + 2], w2, a2);
        a0 = fmaf(x[s3 * 3 + 0], w3, a0); a1 = fmaf(x[s3 * 3 + 1], w3, a1); a2 = fmaf(x[s3 * 3 + 2], w3, a2);
    }
    for (; e < e1; ++e) {
        int s = src_sorted[e];
        float nrm = dinv[s] * dv;
        a0 = fmaf(x[s * 3 + 0], nrm, a0);
        a1 = fmaf(x[s * 3 + 1], nrm, a1);
        a2 = fmaf(x[s * 3 + 2], nrm, a2);
    }
    xa[v * 4 + 0] = a0;
    xa[v * 4 + 1] = a1;
    xa[v * 4 + 2] = a2;
}

// Act[v,c] = relu(xa[v,:3] . W1[:,c] + b1[c]);  zero padding rows
__global__ void k_feat(const float* __restrict__ xa, const float* __restrict__ W1,
                       const float* __restrict__ b1, float* __restrict__ Act, int n) {
    int idx = blockIdx.x * blockDim.x + threadIdx.x;
    int v = idx >> 7, c = idx & 127;
    float r = 0.0f;
    if (v < n) {
        r = fmaf(xa[v * 4 + 0], W1[c],
            fmaf(xa[v * 4 + 1], W1[HID + c],
            fmaf(xa[v * 4 + 2], W1[2 * HID + c], b1[c])));
        r = fmaxf(r, 0.0f);
    }
    Act[idx] = r;
}

// ---------------------------------------------------------------------------
// [Npad,128] @ [128,128] -> [Npad,128].  256 thr, 32 rows/block, 4x4 float4 tile.
// ---------------------------------------------------------------------------
__global__ __launch_bounds__(256) void k_gemm128(const float* __restrict__ X,
                                                 const float* __restrict__ W,
                                                 float* __restrict__ Hout) {
    int cg = threadIdx.x & 31;
    int rg = threadIdx.x >> 5;
    long row0 = (long)blockIdx.x * 32 + rg * 4;
    const float4* X4 = (const float4*)(X + row0 * HID);
    const float4* W4 = (const float4*)W;

    float4 acc[4];
#pragma unroll
    for (int r = 0; r < 4; ++r) acc[r] = make_float4(0.f, 0.f, 0.f, 0.f);

#pragma unroll 4
    for (int k4 = 0; k4 < 32; ++k4) {
        float4 x[4];
#pragma unroll
        for (int r = 0; r < 4; ++r) x[r] = X4[r * 32 + k4];
#pragma unroll
        for (int dk = 0; dk < 4; ++dk) {
            float4 w = W4[(k4 * 4 + dk) * 32 + cg];
#pragma unroll
            for (int r = 0; r < 4; ++r) {
                float xs = (dk == 0) ? x[r].x : (dk == 1) ? x[r].y
                         : (dk == 2) ? x[r].z : x[r].w;
                acc[r].x = fmaf(xs, w.x, acc[r].x);
                acc[r].y = fmaf(xs, w.y, acc[r].y);
                acc[r].z = fmaf(xs, w.z, acc[r].z);
                acc[r].w = fmaf(xs, w.w, acc[r].w);
            }
        }
    }

    float4* O4 = (float4*)(Hout + row0 * HID);
#pragma unroll
    for (int r = 0; r < 4; ++r) O4[r * 32 + cg] = acc[r];
}

// ---------------------------------------------------------------------------
// Fused aggregation, wave per node, 4-deep MLP unroll.
// ---------------------------------------------------------------------------
__global__ __launch_bounds__(256) void k_gather(const float* __restrict__ Hin,
                                                const int* __restrict__ row_start,
                                                const int* __restrict__ src_sorted,
                                                const float* __restrict__ dinv,
                                                const float* __restrict__ bias,
                                                float* __restrict__ Aout, int n) {
    int wid  = (blockIdx.x * blockDim.x + threadIdx.x) >> 6;
    int lane = threadIdx.x & 63;
    if (wid >= n) return;
    int v = wid;
    float dv = dinv[v];
    float2 hv = *(const float2*)&Hin[(size_t)v * HID + 2 * lane];
    float2 acc = make_float2(hv.x * dv * dv, hv.y * dv * dv);
    int e1 = row_start[v + 1];
    int e = row_start[v];
    for (; e + 4 <= e1; e += 4) {
        int s0 = src_sorted[e + 0], s1 = src_sorted[e + 1];
        int s2 = src_sorted[e + 2], s3 = src_sorted[e + 3];
        float w0 = dinv[s0] * dv, w1 = dinv[s1] * dv;
        float w2 = dinv[s2] * dv, w3 = dinv[s3] * dv;
        float2 h0 = *(const float2*)&Hin[(size_t)s0 * HID + 2 * lane];
        float2 h1 = *(const float2*)&Hin[(size_t)s1 * HID + 2 * lane];
        float2 h2 = *(const float2*)&Hin[(size_t)s2 * HID + 2 * lane];
        float2 h3 = *(const float2*)&Hin[(size_t)s3 * HID + 2 * lane];
        acc.x = fmaf(h0.x, w0, acc.x); acc.y = fmaf(h0.y, w0, acc.y);
        acc.x = fmaf(h1.x, w1, acc.x); acc.y = fmaf(h1.y, w1, acc.y);
        acc.x = fmaf(h2.x, w2, acc.x); acc.y = fmaf(h2.y, w2, acc.y);
        acc.x = fmaf(h3.x, w3, acc.x); acc.y = fmaf(h3.y, w3, acc.y);
    }
    for (; e < e1; ++e) {
        int s = src_sorted[e];
        float nrm = dinv[s] * dv;
        float2 hs = *(const float2*)&Hin[(size_t)s * HID + 2 * lane];
        acc.x = fmaf(hs.x, nrm, acc.x);
        acc.y = fmaf(hs.y, nrm, acc.y);
    }
    float2 bb = *(const float2*)&bias[2 * lane];
    acc.x = fmaxf(acc.x + bb.x, 0.0f);
    acc.y = fmaxf(acc.y + bb.y, 0.0f);
    *(float2*)&Aout[(size_t)v * HID + 2 * lane] = acc;
}

// Layer-3 variant: same gather + bias + relu, then project row onto W4p [128,2]
// and write only float2 P3[v].  Wave-reduce via shfl.
__global__ __launch_bounds__(256) void k_gather_proj(const float* __restrict__ Hin,
                                                     const int* __restrict__ row_start,
                                                     const int* __restrict__ src_sorted,
                                                     const float* __restrict__ dinv,
                                                     const float* __restrict__ bias,
                                                     const float* __restrict__ W4p,
                                                     float* __restrict__ P3, int n) {
    int wid  = (blockIdx.x * blockDim.x + threadIdx.x) >> 6;
    int lane = threadIdx.x & 63;
    if (wid >= n) return;
    int v = wid;
    float dv = dinv[v];
    float2 hv = *(const float2*)&Hin[(size_t)v * HID + 2 * lane];
    float2 acc = make_float2(hv.x * dv * dv, hv.y * dv * dv);
    int e1 = row_start[v + 1];
    int e = row_start[v];
    for (; e + 4 <= e1; e += 4) {
        int s0 = src_sorted[e + 0], s1 = src_sorted[e + 1];
        int s2 = src_sorted[e + 2], s3 = src_sorted[e + 3];
        float w0 = dinv[s0] * dv, w1 = dinv[s1] * dv;
        float w2 = dinv[s2] * dv, w3 = dinv[s3] * dv;
        float2 h0 = *(const float2*)&Hin[(size_t)s0 * HID + 2 * lane];
        float2 h1 = *(const float2*)&Hin[(size_t)s1 * HID + 2 * lane];
        float2 h2 = *(const float2*)&Hin[(size_t)s2 * HID + 2 * lane];
        float2 h3 = *(const float2*)&Hin[(size_t)s3 * HID + 2 * lane];
        acc.x = fmaf(h0.x, w0, acc.x); acc.y = fmaf(h0.y, w0, acc.y);
        acc.x = fmaf(h1.x, w1, acc.x); acc.y = fmaf(h1.y, w1, acc.y);
        acc.x = fmaf(h2.x, w2, acc.x); acc.y = fmaf(h2.y, w2, acc.y);
        acc.x = fmaf(h3.x, w3, acc.x); acc.y = fmaf(h3.y, w3, acc.y);
    }
    for (; e < e1; ++e) {
        int s = src_sorted[e];
        float nrm = dinv[s] * dv;
        float2 hs = *(const float2*)&Hin[(size_t)s * HID + 2 * lane];
        acc.x = fmaf(hs.x, nrm, acc.x);
        acc.y = fmaf(hs.y, nrm, acc.y);
    }
    float2 bb = *(const float2*)&bias[2 * lane];
    acc.x = fmaxf(acc.x + bb.x, 0.0f);
    acc.y = fmaxf(acc.y + bb.y, 0.0f);
    // project: lane holds k = 2*lane, 2*lane+1;  W4p row-major [k][c]
    float4 w = *(const float4*)&W4p[lane * 4];
    float p0 = acc.x * w.x + acc.y * w.z;
    float p1 = acc.x * w.y + acc.y * w.w;
#pragma unroll
    for (int off = 32; off; off >>= 1) {
        p0 += __shfl_down(p0, off);
        p1 += __shfl_down(p1, off);
    }
    if (lane == 0) *(float2*)&P3[v * 2] = make_float2(p0, p1);
}

// Layer 4 (2-wide, P3 is ~400 KB -> cache-resident) fused with pooling.
__global__ void k_gather2pool(const float* __restrict__ P3, const int* __restrict__ row_start,
                              const int* __restrict__ src_sorted, const float* __restrict__ dinv,
                              const int* __restrict__ batch, float* __restrict__ sums2,
                              float* __restrict__ cnt, int n) {
    int v = blockIdx.x * blockDim.x + threadIdx.x;
    if (v >= n) return;
    float dv = dinv[v];
    float2 pv = *(const float2*)&P3[v * 2];
    float ax = pv.x * dv * dv, ay = pv.y * dv * dv;
    int e1 = row_start[v + 1];
    int e = row_start[v];
    for (; e + 4 <= e1; e += 4) {
        int s0 = src_sorted[e + 0], s1 = src_sorted[e + 1];
        int s2 = src_sorted[e + 2], s3 = src_sorted[e + 3];
        float w0 = dinv[s0] * dv, w1 = dinv[s1] * dv;
        float w2 = dinv[s2] * dv, w3 = dinv[s3] * dv;
        float2 p0 = *(const float2*)&P3[s0 * 2];
        float2 p1 = *(const float2*)&P3[s1 * 2];
        float2 p2 = *(const float2*)&P3[s2 * 2];
        float2 p3 = *(const float2*)&P3[s3 * 2];
        ax = fmaf(p0.x, w0, ax); ay = fmaf(p0.y, w0, ay);
        ax = fmaf(p1.x, w1, ax); ay = fmaf(p1.y, w1, ay);
        ax = fmaf(p2.x, w2, ax); ay = fmaf(p2.y, w2, ay);
        ax = fmaf(p3.x, w3, ax); ay = fmaf(p3.y, w3, ay);
    }
    for (; e < e1; ++e) {
        int s = src_sorted[e];
        float nrm = dinv[s] * dv;
        float2 ps = *(const float2*)&P3[s * 2];
        ax = fmaf(ps.x, nrm, ax);
        ay = fmaf(ps.y, nrm, ay);
    }
    int g = batch[v];
    atomicAdd(&sums2[g * 2 + 0], ax);
    atomicAdd(&sums2[g * 2 + 1], ay);
    atomicAdd(&cnt[g], 1.0f);
}

// out[g,c] = sums2[g,c]/max(cnt,1) + b4p[c]
__global__ void k_final2(const float* __restrict__ sums2, const float* __restrict__ cnt,
                         const float* __restrict__ b4p, float* __restrict__ out) {
    int idx = blockIdx.x * blockDim.x + threadIdx.x;
    if (idx >= NGRAPH * 2) return;
    int g = idx >> 1, c = idx & 1;
    out[idx] = sums2[idx] / fmaxf(cnt[g], 1.0f) + b4p[c];
}

// ---------------------------------------------------------------------------

extern "C" void kernel_launch(void* const* d_in, const int* in_sizes, int n_in,
                              void* d_out, int out_size, void* d_ws, size_t ws_size,
                              hipStream_t stream) {
    const float* x    = (const float*)d_in[0];
    const float* W1   = (const float*)d_in[1];
    const float* b1   = (const float*)d_in[2];
    const float* W2   = (const float*)d_in[3];
    const float* b2   = (const float*)d_in[4];
    const float* W3   = (const float*)d_in[5];
    const float* b3   = (const float*)d_in[6];
    const float* W4   = (const float*)d_in[7];
    const float* b4   = (const float*)d_in[8];
    const float* linW = (const float*)d_in[9];
    const float* linb = (const float*)d_in[10];
    const int*   ei   = (const int*)d_in[11];   // [2,E]
    const int*   batch= (const int*)d_in[12];   // [N]
    float* out        = (float*)d_out;

    const int N = in_sizes[0] / 3;
    const int E = in_sizes[11] / 2;
    const int NPAD = ((N + 31) / 32) * 32;
    const int NB1024 = (N + 1023) / 1024;

    // Workspace layout (4-B slots)
    float* ws = (float*)d_ws;
    float* dinv       = ws;                            // 50176
    int*   deg_i      = (int*)(ws + 50176);            // 50176
    int*   row_start  = (int*)(ws + 100352);           // 50432 (N+1)
    int*   cursor     = (int*)(ws + 150784);           // 50176
    int*   bsum       = (int*)(ws + 200960);           // 64
    float* W4p        = ws + 201024;                   // 256
    float* b4p        = ws + 201280;                   // 64 (2 used)
    int*   src_sorted = (int*)(ws + 201344);           // 600064
    float* Xa         = ws + 801408;                   // N*4
    float* P3         = ws + 1002112;                  // N*2 (pad 100352)
    float* Hbuf       = ws + 1102464;                  // NPAD*128
    float* Act        = Hbuf + (size_t)NPAD * HID;     // NPAD*128
    float* Sums2      = Act + (size_t)NPAD * HID;      // 1024
    float* Cnt        = Sums2 + NGRAPH * 2;            // 512

    const int B = 256;

    // --- CSR setup ---
    hipMemsetAsync(deg_i, 0, N * sizeof(int), stream);
    hipMemsetAsync(Sums2, 0, (NGRAPH * 2 + NGRAPH) * sizeof(float), stream);
    k_count<<<(E + B - 1) / B, B, 0, stream>>>(ei, deg_i, E);
    k_bsum<<<NB1024, 1024, 0, stream>>>(deg_i, bsum, N);
    k_scan2<<<NB1024, 1024, 0, stream>>>(deg_i, bsum, row_start, cursor, dinv, N, NB1024);
    k_fill<<<(E + B - 1) / B, B, 0, stream>>>(ei, cursor, src_sorted, E);
    k_foldW<<<1, 256, 0, stream>>>(W4, linW, b4, linb, W4p, b4p);

    const int gatherBlocks = (N + 3) / 4;      // 4 waves / 256-thr block
    const int gemmBlocks   = NPAD / 32;

    // --- Layer 1 (reordered) ---
    k_gather3<<<(N + B - 1) / B, B, 0, stream>>>(x, row_start, src_sorted, dinv, Xa, N);
    k_feat<<<(NPAD * HID) / B, B, 0, stream>>>(Xa, W1, b1, Act, N);
    // --- Layer 2 ---
    k_gemm128<<<gemmBlocks, B, 0, stream>>>(Act, W2, Hbuf);
    k_gather<<<gatherBlocks, B, 0, stream>>>(Hbuf, row_start, src_sorted, dinv, b2, Act, N);
    // --- Layer 3 (gather fused with W4p projection -> 2-wide P3) ---
    k_gemm128<<<gemmBlocks, B, 0, stream>>>(Act, W3, Hbuf);
    k_gather_proj<<<gatherBlocks, B, 0, stream>>>(Hbuf, row_start, src_sorted, dinv, b3, W4p, P3, N);
    // --- Layer 4 (2-wide gather fused with pooling) ---
    k_gather2pool<<<(N + B - 1) / B, B, 0, stream>>>(P3, row_start, src_sorted, dinv, batch, Sums2, Cnt, N);

    // --- Head ---
    k_final2<<<(NGRAPH * 2 + B - 1) / B, B, 0, stream>>>(Sums2, Cnt, b4p, out);
}